// Round 8
// baseline (279.795 us; speedup 1.0000x reference)
//
#include <hip/hip_runtime.h>

#ifndef __has_builtin
#define __has_builtin(x) 0
#endif

__device__ __forceinline__ float fast_exp2(float x) {
#if __has_builtin(__builtin_amdgcn_exp2f)
    return __builtin_amdgcn_exp2f(x);
#else
    return exp2f(x);
#endif
}

// Wave64 sum via DPP on the VALU pipe: row_shr 1/2/4/8 (+bound_ctrl),
// row_bcast15, row_bcast31. Lane 63 ends with the full 64-lane sum.
__device__ __forceinline__ float wave_sum_dpp(float x) {
    int v;
    v = __builtin_amdgcn_update_dpp(0, __float_as_int(x), 0x111, 0xf, 0xf, true);
    x += __int_as_float(v);
    v = __builtin_amdgcn_update_dpp(0, __float_as_int(x), 0x112, 0xf, 0xf, true);
    x += __int_as_float(v);
    v = __builtin_amdgcn_update_dpp(0, __float_as_int(x), 0x114, 0xf, 0xf, true);
    x += __int_as_float(v);
    v = __builtin_amdgcn_update_dpp(0, __float_as_int(x), 0x118, 0xf, 0xf, true);
    x += __int_as_float(v);
    v = __builtin_amdgcn_update_dpp(0, __float_as_int(x), 0x142, 0xa, 0xf, false);
    x += __int_as_float(v);
    v = __builtin_amdgcn_update_dpp(0, __float_as_int(x), 0x143, 0xc, 0xf, false);
    x += __int_as_float(v);
    return x;
}

constexpr int   kB      = 256;
constexpr int   kC      = 1024;
constexpr int   kG      = 13;
constexpr int   kP      = kG * kG;                // 169
constexpr int   kPP     = 16;                     // positions per part
constexpr int   kParts  = 11;                     // 11*16 = 176 >= 169
constexpr float kEps    = 1e-6f;
constexpr float kZ      = 17.079468445347132f;    // 2*pi*e
constexpr float kLog2e  = 1.4426950408889634f;
constexpr float kInv169 = 1.0f / 169.0f;
constexpr float kScale  = 1.0f / (256.0f * 1024.0f);

// ---------------------------------------------------------------------------
// Kernel 1: single-HBM-read partial stats with HIGH block residency.
// Block = (part of 16 consecutive positions, batch b), 256 threads,
// __launch_bounds__(256,4): ~100 VGPRs -> 4 blocks (16 waves) resident/CU,
// so one block's __syncthreads overlaps other blocks' memory (fixes R7's
// single-resident-block full-drain barriers).
// Thread owns channels 4*tid..4*tid+3: one float4 per position, 16
// independent dwordx4 loads in flight. Denominator per position: 3 lane
// adds + 6 DPP adds + 1 lane-63 LDS write (16 DS ops/wave total), 4-way
// tree, invD broadcast. Stats accumulate from registers; float4 stores.
// Tail part masks p>168 (loads clamped in-bounds, e zeroed).
// ---------------------------------------------------------------------------
__global__ __launch_bounds__(256, 4)
void part_stats_kernel(const float* __restrict__ x, float* __restrict__ ws)
{
    __shared__ float sP[kPP * 4];
    __shared__ float sInvD[kPP];

    const int tid  = threadIdx.x;
    const int lane = tid & 63;
    const int wid  = tid >> 6;
    const int part = blockIdx.x >> 8;          // 0..10
    const int b    = blockIdx.x & 255;
    const int p0   = part * kPP;

    const float* __restrict__ xb = x + (size_t)b * kP * kC + 4 * tid;

    float4 v[kPP];
    #pragma unroll
    for (int i = 0; i < kPP; ++i) {
        const int p  = p0 + i;
        const int pc = (p <= kP - 1) ? p : (kP - 1);   // clamp: stay in-bounds
        v[i] = *(const float4*)(xb + (size_t)pc * kC);
    }

    float e[kPP][4];
    #pragma unroll
    for (int i = 0; i < kPP; ++i) {
        const float m = (p0 + i <= kP - 1) ? 1.0f : 0.0f;
        e[i][0] = fast_exp2(v[i].x * kLog2e) * m;
        e[i][1] = fast_exp2(v[i].y * kLog2e) * m;
        e[i][2] = fast_exp2(v[i].z * kLog2e) * m;
        e[i][3] = fast_exp2(v[i].w * kLog2e) * m;
    }

    #pragma unroll
    for (int i = 0; i < kPP; ++i) {
        float s = (e[i][0] + e[i][1]) + (e[i][2] + e[i][3]);
        s = wave_sum_dpp(s);
        if (lane == 63) sP[i * 4 + wid] = s;
    }
    __syncthreads();

    if (tid < kPP) {
        const float d = (sP[tid * 4 + 0] + sP[tid * 4 + 1]) +
                        (sP[tid * 4 + 2] + sP[tid * 4 + 3]);
        sInvD[tid] = 1.0f / (d + 1e-30f);      // masked position: 0*huge = 0
    }
    __syncthreads();

    float S0[4] = {0,0,0,0}, S1x[4] = {0,0,0,0}, S1y[4] = {0,0,0,0};
    float S2x[4] = {0,0,0,0}, S2y[4] = {0,0,0,0};

    #pragma unroll
    for (int i = 0; i < kPP; ++i) {
        const float iv = sInvD[i];
        const int   p  = p0 + i;
        const int   h  = p / kG;               // magic-mul div
        const int   w  = p - h * kG;
        const float fx = (float)(h + 1);
        const float fy = (float)(w + 1);
        const float fx2 = fx * fx, fy2 = fy * fy;
        #pragma unroll
        for (int j = 0; j < 4; ++j) {
            const float f = e[i][j] * iv;
            S0[j]  += f;
            S1x[j]  = fmaf(fx,  f, S1x[j]);
            S1y[j]  = fmaf(fy,  f, S1y[j]);
            S2x[j]  = fmaf(fx2, f, S2x[j]);
            S2y[j]  = fmaf(fy2, f, S2y[j]);
        }
    }

    // ws[part][b][stat][c], float4 store at c = 4*tid
    float* __restrict__ o = ws + (((size_t)part * kB + b) * 5) * kC + 4 * tid;
    *(float4*)(o + 0 * kC) = make_float4(S0[0],  S0[1],  S0[2],  S0[3]);
    *(float4*)(o + 1 * kC) = make_float4(S1x[0], S1x[1], S1x[2], S1x[3]);
    *(float4*)(o + 2 * kC) = make_float4(S1y[0], S1y[1], S1y[2], S1y[3]);
    *(float4*)(o + 3 * kC) = make_float4(S2x[0], S2x[1], S2x[2], S2x[3]);
    *(float4*)(o + 4 * kC) = make_float4(S2y[0], S2y[1], S2y[2], S2y[3]);
}

// ---------------------------------------------------------------------------
// Kernel 2: combine 11 parts per (b,c), det epilogue, global mean.
// ---------------------------------------------------------------------------
__global__ __launch_bounds__(1024, 4)
void combine_kernel(const float* __restrict__ ws, float* __restrict__ out)
{
    __shared__ float sred[16];

    const int tid  = threadIdx.x;
    const int lane = tid & 63;
    const int wid  = tid >> 6;
    const int b    = blockIdx.x;

    float S0 = 0.f, S1x = 0.f, S1y = 0.f, S2x = 0.f, S2y = 0.f;
    #pragma unroll
    for (int part = 0; part < kParts; ++part) {
        const float* __restrict__ o = ws + (((size_t)part * kB + b) * 5) * kC + tid;
        S0  += o[0 * kC];
        S1x += o[1 * kC];
        S1y += o[2 * kC];
        S2x += o[3 * kC];
        S2y += o[4 * kC];
    }

    const float s   = S0 + kEps;
    const float is  = 1.0f / s;
    const float mx  = S1x * is;
    const float my  = S1y * is;
    const float nx  = S2x - mx * (2.0f * S1x - mx * S0);
    const float ny  = S2y - my * (2.0f * S1y - my * S0);
    const float t   = (nx + ny) * is * kInv169;
    float det = t * t * kZ;

    #pragma unroll
    for (int m = 1; m < 64; m <<= 1)
        det += __shfl_xor(det, m);

    if (lane == 0) sred[wid] = det;
    __syncthreads();
    if (wid == 0) {
        float v = (lane < 16) ? sred[lane] : 0.0f;
        #pragma unroll
        for (int m = 1; m < 16; m <<= 1)
            v += __shfl_xor(v, m);
        if (lane == 0) atomicAdd(out, v * kScale);
    }
}

extern "C" void kernel_launch(void* const* d_in, const int* in_sizes, int n_in,
                              void* d_out, int out_size, void* d_ws, size_t ws_size,
                              hipStream_t stream)
{
    const float* x   = (const float*)d_in[0];
    float*       out = (float*)d_out;
    float*       ws  = (float*)d_ws;   // 11*256*5*1024 floats = 57.7 MB

    hipMemsetAsync(out, 0, sizeof(float) * (size_t)out_size, stream);
    part_stats_kernel<<<dim3(kParts * kB), dim3(256), 0, stream>>>(x, ws);
    combine_kernel  <<<dim3(kB),           dim3(1024), 0, stream>>>(ws, out);
}